// Round 5
// baseline (479.180 us; speedup 1.0000x reference)
//
#include <hip/hip_runtime.h>
#include <math.h>

#define NTOK 4096
#define DMODEL 256
#define G_GENES 2000

typedef _Float16 f16;
typedef _Float16 f16x8 __attribute__((ext_vector_type(8)));
typedef float f32x4 __attribute__((ext_vector_type(4)));

// ---------------- helpers ----------------
__device__ __forceinline__ float gelu_exact(float x) {
    return 0.5f * x * (1.0f + erff(x * 0.70710678118654752f));
}
__device__ __forceinline__ float softplus_fast(float x) {
    return fmaxf(x, 0.0f) + __logf(1.0f + __expf(-fabsf(x)));
}

// ---------------- encoder input build: vis cvt + fourier, one block per token ----------------
__global__ __launch_bounds__(256) void encin_k(const float* __restrict__ vis,
                                               const float* __restrict__ pos,
                                               const float* __restrict__ B,
                                               f16* __restrict__ Abig) {
    int n = blockIdx.x, t = threadIdx.x;
    float4 v = *(const float4*)(vis + (size_t)n * 1024 + t * 4);
    union { ushort4 u; f16 h[4]; } o;
    o.h[0] = (f16)v.x; o.h[1] = (f16)v.y; o.h[2] = (f16)v.z; o.h[3] = (f16)v.w;
    *(ushort4*)(Abig + (size_t)n * 1152 + t * 4) = o.u;
    if (t < 64) {
        float xp = 6.283185307179586f *
                   (pos[n * 3 + 0] * B[t] + pos[n * 3 + 1] * B[64 + t] + pos[n * 3 + 2] * B[128 + t]);
        Abig[(size_t)n * 1152 + 1024 + t] = (f16)sinf(xp);
        Abig[(size_t)n * 1152 + 1088 + t] = (f16)cosf(xp);
    }
}

// ---------------- batched transpose-convert, flat tile list ----------------
struct TD { const float* s; f16* d; int R, C; int ldo; };
struct TDs { TD t[17]; int pre[18]; };
__global__ __launch_bounds__(256) void tconv_k(TDs ds) {
    int bid = blockIdx.x;
    int ti = 0;
#pragma unroll
    for (int i = 0; i < 17; i++)
        if (bid >= ds.pre[i + 1]) ti = i + 1;
    TD td = ds.t[ti];
    int local = bid - ds.pre[ti];
    int yt = td.C >> 5;
    int r0 = (local / yt) << 5;
    int c0 = (local % yt) << 5;
    __shared__ float tile[32][33];
    int tx = threadIdx.x & 31, ty = threadIdx.x >> 5;
#pragma unroll
    for (int i = 0; i < 32; i += 8)
        tile[ty + i][tx] = td.s[(size_t)(r0 + ty + i) * td.C + c0 + tx];
    __syncthreads();
#pragma unroll
    for (int i = 0; i < 32; i += 8)
        td.d[(size_t)(c0 + ty + i) * td.ldo + r0 + tx] = (f16)tile[tx][ty + i];
}

// ---------------- f16 transpose (V^T from qkv buffer) ----------------
__global__ __launch_bounds__(256) void tconvh_k(const f16* __restrict__ src, int ldin,
                                                f16* __restrict__ dst, int ldo) {
    __shared__ f16 tile[32][33];
    int r0 = blockIdx.x * 32, c0 = blockIdx.y * 32;
    int tx = threadIdx.x & 31, ty = threadIdx.x >> 5;
#pragma unroll
    for (int i = 0; i < 32; i += 8)
        tile[ty + i][tx] = src[(size_t)(r0 + ty + i) * ldin + c0 + tx];
    __syncthreads();
#pragma unroll
    for (int i = 0; i < 32; i += 8)
        dst[(size_t)(c0 + ty + i) * ldo + r0 + tx] = tile[tx][ty + i];
}

// ---------------- setup: fused bias vectors ----------------
__global__ __launch_bounds__(256) void setup_k(const float* b_img, const float* b_pos,
                                               const float* bq, const float* bk, const float* bv,
                                               const float* bg1, const float* bf1,
                                               float* benc, float* biasqkv, float* bgf) {
    int t = threadIdx.x;
    benc[t] = b_img[t] + b_pos[t];
    biasqkv[t] = bq[t];
    biasqkv[256 + t] = bk[t];
    biasqkv[512 + t] = bv[t];
    bgf[t] = bg1[t];
    if (t < 64) bgf[256 + t] = bf1[t];
}

// ---------------- MFMA f16 GEMM ----------------
// C[*,Ncols] = epi(A[*,K](f16) @ B^T + bias), B as [Ncols, K] f16.
// BM=128, BN=MTN*32, BK=64; 256 threads = 4 waves 2x2; wave tile 64 x (MTN*16).
// MODE 0: plain. MODE 1: MoE-up (expert temap[bx], A rows via gidx).
// MODE 2: MoE-down (expert temap[bx], scatter epilogue).
#define EPI_F32 0
#define EPI_DUAL 1
#define EPI_F16 2
#define EPI_GELU_F16 3
#define EPI_GENE 4
#define EPI_MOESC 5
#define EPI_GF 6

template <int MTN, int EPI, int MODE>
__global__ __launch_bounds__(256) void bgemm_k(
    const f16* __restrict__ A, int lda,
    const f16* __restrict__ B, int ldb,
    const float* __restrict__ bias,
    float* __restrict__ Cf, f16* __restrict__ Ch, int ldc,
    int Ncols, int K,
    size_t eB, size_t eBias,
    const int* __restrict__ gidx, const int* __restrict__ temap,
    const float* __restrict__ z2, const float* __restrict__ gval,
    float* __restrict__ outMu, float* __restrict__ outTheta) {
    constexpr int BN = MTN * 32;
    __shared__ __align__(16) char smem[(128 + BN) * 72 * 2];
    f16 (*As)[72] = (f16(*)[72])smem;
    f16 (*Bs)[72] = (f16(*)[72])(smem + (size_t)128 * 72 * 2);

    const int tid = threadIdx.x;
    const int m0 = blockIdx.x * 128;
    const int n0 = blockIdx.y * BN;
    const int w = tid >> 6, lane = tid & 63;
    const int wr = w >> 1, wc = w & 1;
    const int ln = lane & 15, lg = lane >> 4;
    const int sr = tid >> 3;
    const int sc = (tid & 7) * 8;

    if (MODE == 1 || MODE == 2) {
        int e = temap[blockIdx.x];
        B += (size_t)e * eB;
        if (bias) bias += (size_t)e * eBias;
    }

    int grows[4];
#pragma unroll
    for (int i = 0; i < 4; i++) {
        int r = m0 + sr + i * 32;
        if (MODE == 1) {
            int g = gidx[r];
            grows[i] = (g < 0) ? 0 : g;
        } else {
            grows[i] = r;
        }
    }

    f32x4 acc[4][MTN];
    f32x4 zf = {0.f, 0.f, 0.f, 0.f};
#pragma unroll
    for (int i = 0; i < 4; i++)
#pragma unroll
        for (int j = 0; j < MTN; j++) acc[i][j] = zf;

    for (int k0 = 0; k0 < K; k0 += 64) {
#pragma unroll
        for (int i = 0; i < 4; i++) {
            uint4 v = *(const uint4*)(A + (size_t)grows[i] * lda + k0 + sc);
            int r = sr + i * 32;
            *(uint2*)&As[r][sc] = make_uint2(v.x, v.y);
            *(uint2*)&As[r][sc + 4] = make_uint2(v.z, v.w);
        }
#pragma unroll
        for (int i = 0; i < MTN; i++) {
            int r = sr + i * 32;
            uint4 v = make_uint4(0, 0, 0, 0);
            if (n0 + r < Ncols) v = *(const uint4*)(B + (size_t)(n0 + r) * ldb + k0 + sc);
            *(uint2*)&Bs[r][sc] = make_uint2(v.x, v.y);
            *(uint2*)&Bs[r][sc + 4] = make_uint2(v.z, v.w);
        }
        __syncthreads();
#pragma unroll
        for (int ks = 0; ks < 64; ks += 32) {
            f16x8 a[4], b[MTN];
#pragma unroll
            for (int t = 0; t < 4; t++) {
                const f16* p = &As[wr * 64 + t * 16 + ln][ks + lg * 8];
                union { f16x8 f; uint2 u[2]; } tmp;
                tmp.u[0] = *(const uint2*)p;
                tmp.u[1] = *(const uint2*)(p + 4);
                a[t] = tmp.f;
            }
#pragma unroll
            for (int t = 0; t < MTN; t++) {
                const f16* p = &Bs[wc * (MTN * 16) + t * 16 + ln][ks + lg * 8];
                union { f16x8 f; uint2 u[2]; } tmp;
                tmp.u[0] = *(const uint2*)p;
                tmp.u[1] = *(const uint2*)(p + 4);
                b[t] = tmp.f;
            }
#pragma unroll
            for (int tm = 0; tm < 4; tm++)
#pragma unroll
                for (int tn = 0; tn < MTN; tn++)
                    acc[tm][tn] = __builtin_amdgcn_mfma_f32_16x16x32_f16(a[tm], b[tn], acc[tm][tn], 0, 0, 0);
        }
        __syncthreads();
    }

    if (EPI == EPI_GENE) {
        float bval[MTN];
#pragma unroll
        for (int tn = 0; tn < MTN; tn++) {
            int col = n0 + wc * (MTN * 16) + tn * 16 + ln;
            bval[tn] = (col < Ncols) ? bias[col] : 0.0f;
        }
        float* Cs = (float*)smem;
        const int rrow = tid >> 3;
        const int rseg = tid & 7;
#pragma unroll
        for (int tm = 0; tm < 4; tm++) {
            __syncthreads();
#pragma unroll
            for (int tn = 0; tn < MTN; tn++) {
                int lc = wc * (MTN * 16) + tn * 16 + ln;
#pragma unroll
                for (int i = 0; i < 4; i++) {
                    int lr = wr * 16 + lg * 4 + i;
                    Cs[lr * 132 + lc] = acc[tm][tn][i] + bval[tn];
                }
            }
            __syncthreads();
            int grow = m0 + ((rrow >> 4) * 64) + tm * 16 + (rrow & 15);
            const float* cr = &Cs[rrow * 132 + rseg * 16];
            float mu[8], th[8];
#pragma unroll
            for (int g = 0; g < 8; g++) {
                mu[g] = softplus_fast(cr[2 * g]);
                th[g] = softplus_fast(cr[2 * g + 1]) + 1e-6f;
            }
            int gbase = (n0 + rseg * 16) >> 1;
            float* mp = outMu + (size_t)grow * G_GENES + gbase;
            float* tp = outTheta + (size_t)grow * G_GENES + gbase;
            if (gbase + 8 <= G_GENES) {
                *(float4*)mp = make_float4(mu[0], mu[1], mu[2], mu[3]);
                *(float4*)(mp + 4) = make_float4(mu[4], mu[5], mu[6], mu[7]);
                *(float4*)tp = make_float4(th[0], th[1], th[2], th[3]);
                *(float4*)(tp + 4) = make_float4(th[4], th[5], th[6], th[7]);
            } else {
#pragma unroll
                for (int g = 0; g < 8; g++)
                    if (gbase + g < G_GENES) { mp[g] = mu[g]; tp[g] = th[g]; }
            }
        }
        return;
    }

#pragma unroll
    for (int tm = 0; tm < 4; tm++) {
#pragma unroll
        for (int tn = 0; tn < MTN; tn++) {
            int col = n0 + wc * (MTN * 16) + tn * 16 + ln;
            if (col >= Ncols) continue;
#pragma unroll
            for (int i = 0; i < 4; i++) {
                int row = m0 + wr * 64 + tm * 16 + lg * 4 + i;
                float v = acc[tm][tn][i];
                if (EPI == EPI_MOESC) {
                    int tok = gidx[row];
                    if (tok < 0) continue;
                    v += bias[col];
                    size_t oi = (size_t)tok * ldc + col;
                    Ch[oi] = (f16)(z2[oi] + gval[tok] * v);
                    continue;
                }
                if (EPI == EPI_GF) {
                    v += bias[col];
                    if (col < 256) Cf[(size_t)row * 256 + col] = v;
                    else Ch[(size_t)row * 64 + (col - 256)] = (f16)gelu_exact(v);
                    continue;
                }
                size_t idx = (size_t)row * ldc + col;
                if (EPI == EPI_F32) {
                    if (bias) v += bias[col];
                    Cf[idx] = v;
                } else if (EPI == EPI_DUAL) {
                    v += bias[col];
                    Cf[idx] = v;
                    Ch[idx] = (f16)v;
                } else if (EPI == EPI_F16) {
                    v += bias[col];
                    Ch[idx] = (f16)v;
                } else if (EPI == EPI_GELU_F16) {
                    v += bias[col];
                    Ch[idx] = (f16)gelu_exact(v);
                }
            }
        }
    }
}

// ---------------- flash attention, split-KV x8, swizzled f16 partials ----------------
// grid (64 q-tiles, 4 heads, 8 kv-splits); 256 thr = 4 waves; wave owns 16 Q rows.
// Opart16 layout: [((s*256 + slot)*4 + w)*64 + lane] * 16  (lane-contiguous, slot = bx*4+h)
__global__ __launch_bounds__(256) void flash_k(const f16* __restrict__ qkv,
                                               const f16* __restrict__ Vt,
                                               f16* __restrict__ Opart16,
                                               float2* __restrict__ mlpart) {
    __shared__ f16 Ks[64][72];
    __shared__ f16 Vts[64][72];
    __shared__ f16 Ps[4][16][72];
    const int tid = threadIdx.x;
    const int w = tid >> 6, lane = tid & 63;
    const int ln = lane & 15, quad = lane >> 4;
    const int q0 = blockIdx.x * 64;
    const int hq = blockIdx.y * 64;
    const int kt0 = blockIdx.z * 8;

    f16x8 qfrag[2];
    {
        const f16* qp = qkv + (size_t)(q0 + w * 16 + ln) * 768 + hq + quad * 8;
        union { f16x8 f; uint4 u; } t0, t1;
        t0.u = *(const uint4*)qp;
        t1.u = *(const uint4*)(qp + 32);
        qfrag[0] = t0.f; qfrag[1] = t1.f;
    }

    const int srow = tid >> 2;
    const int scol = (tid & 3) * 16;

    float m_run[4], l_run[4];
    f32x4 Oacc[4];
#pragma unroll
    for (int i = 0; i < 4; i++) {
        m_run[i] = -1e30f; l_run[i] = 0.0f;
        Oacc[i] = (f32x4){0.f, 0.f, 0.f, 0.f};
    }

    uint4 kreg[2], vreg[2];
    {
        const f16* kp = qkv + (size_t)(kt0 * 64 + srow) * 768 + 256 + hq + scol;
        const f16* vp = Vt + (size_t)(hq + srow) * 4096 + kt0 * 64 + scol;
        kreg[0] = *(const uint4*)kp; kreg[1] = *(const uint4*)(kp + 8);
        vreg[0] = *(const uint4*)vp; vreg[1] = *(const uint4*)(vp + 8);
    }

    for (int kt = kt0; kt < kt0 + 8; kt++) {
        __syncthreads();
        *(uint4*)&Ks[srow][scol] = kreg[0];
        *(uint4*)&Ks[srow][scol + 8] = kreg[1];
        *(uint4*)&Vts[srow][scol] = vreg[0];
        *(uint4*)&Vts[srow][scol + 8] = vreg[1];
        __syncthreads();
        if (kt + 1 < kt0 + 8) {
            const f16* kp = qkv + (size_t)((kt + 1) * 64 + srow) * 768 + 256 + hq + scol;
            const f16* vp = Vt + (size_t)(hq + srow) * 4096 + (kt + 1) * 64 + scol;
            kreg[0] = *(const uint4*)kp; kreg[1] = *(const uint4*)(kp + 8);
            vreg[0] = *(const uint4*)vp; vreg[1] = *(const uint4*)(vp + 8);
        }

        f32x4 accS[4];
#pragma unroll
        for (int nt = 0; nt < 4; nt++) {
            union { f16x8 f; uint4 u; } b0, b1;
            b0.u = *(const uint4*)&Ks[nt * 16 + ln][quad * 8];
            b1.u = *(const uint4*)&Ks[nt * 16 + ln][32 + quad * 8];
            f32x4 a = {0.f, 0.f, 0.f, 0.f};
            a = __builtin_amdgcn_mfma_f32_16x16x32_f16(qfrag[0], b0.f, a, 0, 0, 0);
            a = __builtin_amdgcn_mfma_f32_16x16x32_f16(qfrag[1], b1.f, a, 0, 0, 0);
            accS[nt] = a;
        }
#pragma unroll
        for (int nt = 0; nt < 4; nt++)
#pragma unroll
            for (int i = 0; i < 4; i++) accS[nt][i] *= 0.125f;

        float mnew[4], alpha[4], rs[4];
#pragma unroll
        for (int i = 0; i < 4; i++) {
            float mx = fmaxf(fmaxf(accS[0][i], accS[1][i]), fmaxf(accS[2][i], accS[3][i]));
            mx = fmaxf(mx, __shfl_xor(mx, 1));
            mx = fmaxf(mx, __shfl_xor(mx, 2));
            mx = fmaxf(mx, __shfl_xor(mx, 4));
            mx = fmaxf(mx, __shfl_xor(mx, 8));
            mnew[i] = fmaxf(m_run[i], mx);
            rs[i] = 0.0f;
        }
#pragma unroll
        for (int nt = 0; nt < 4; nt++)
#pragma unroll
            for (int i = 0; i < 4; i++) {
                float p = __expf(accS[nt][i] - mnew[i]);
                accS[nt][i] = p;
                rs[i] += p;
            }
#pragma unroll
        for (int i = 0; i < 4; i++) {
            float s = rs[i];
            s += __shfl_xor(s, 1);
            s += __shfl_xor(s, 2);
            s += __shfl_xor(s, 4);
            s += __shfl_xor(s, 8);
            alpha[i] = __expf(m_run[i] - mnew[i]);
            l_run[i] = l_run[i] * alpha[i] + s;
            m_run[i] = mnew[i];
        }
#pragma unroll
        for (int dt = 0; dt < 4; dt++)
#pragma unroll
            for (int i = 0; i < 4; i++) Oacc[dt][i] *= alpha[i];

#pragma unroll
        for (int nt = 0; nt < 4; nt++)
#pragma unroll
            for (int i = 0; i < 4; i++)
                Ps[w][quad * 4 + i][nt * 16 + ln] = (f16)accS[nt][i];

        union { f16x8 f; uint4 u; } pf0, pf1;
        pf0.u = *(const uint4*)&Ps[w][ln][quad * 8];
        pf1.u = *(const uint4*)&Ps[w][ln][32 + quad * 8];
#pragma unroll
        for (int dt = 0; dt < 4; dt++) {
            union { f16x8 f; uint4 u; } b0, b1;
            b0.u = *(const uint4*)&Vts[dt * 16 + ln][quad * 8];
            b1.u = *(const uint4*)&Vts[dt * 16 + ln][32 + quad * 8];
            Oacc[dt] = __builtin_amdgcn_mfma_f32_16x16x32_f16(pf0.f, b0.f, Oacc[dt], 0, 0, 0);
            Oacc[dt] = __builtin_amdgcn_mfma_f32_16x16x32_f16(pf1.f, b1.f, Oacc[dt], 0, 0, 0);
        }
    }

    // swizzled, lane-contiguous f16 partial store (2 x 16B per lane)
    const int slot = blockIdx.x * 4 + blockIdx.y;
    f16* op = Opart16 + ((((size_t)blockIdx.z * 256 + slot) * 4 + w) * 64 + lane) * 16;
    union { uint4 u; f16 h[8]; } pk0, pk1;
#pragma unroll
    for (int dt = 0; dt < 2; dt++)
#pragma unroll
        for (int i = 0; i < 4; i++) pk0.h[dt * 4 + i] = (f16)Oacc[dt][i];
#pragma unroll
    for (int dt = 2; dt < 4; dt++)
#pragma unroll
        for (int i = 0; i < 4; i++) pk1.h[(dt - 2) * 4 + i] = (f16)Oacc[dt][i];
    *(uint4*)op = pk0.u;
    *(uint4*)(op + 8) = pk1.u;
    if (ln == 0) {
#pragma unroll
        for (int i = 0; i < 4; i++)
            mlpart[(size_t)(blockIdx.z * 4 + blockIdx.y) * NTOK + q0 + w * 16 + quad * 4 + i] =
                make_float2(m_run[i], l_run[i]);
    }
}

// ---------------- flash combine (de-swizzle): grid 256 blocks x 256 thr ----------------
__global__ __launch_bounds__(256) void fcomb_k(const f16* __restrict__ Opart16,
                                               const float2* __restrict__ mlpart,
                                               f16* __restrict__ ctxbf) {
    const int slot = blockIdx.x;
    const int w = threadIdx.x >> 6, lane = threadIdx.x & 63;
    const int bx = slot >> 2, h = slot & 3;
    const int quad = lane >> 4, ln = lane & 15;
    const int nbase = bx * 64 + w * 16 + quad * 4;

    float2 ml[8][4];
    float mmax[4] = {-1e30f, -1e30f, -1e30f, -1e30f};
#pragma unroll
    for (int s = 0; s < 8; s++)
#pragma unroll
        for (int i = 0; i < 4; i++) {
            ml[s][i] = mlpart[(size_t)(s * 4 + h) * NTOK + nbase + i];
            mmax[i] = fmaxf(mmax[i], ml[s][i].x);
        }
    float L[4] = {0.f, 0.f, 0.f, 0.f};
    float wgt[8][4];
#pragma unroll
    for (int s = 0; s < 8; s++)
#pragma unroll
        for (int i = 0; i < 4; i++) {
            wgt[s][i] = __expf(ml[s][i].x - mmax[i]);
            L[i] += wgt[s][i] * ml[s][i].y;
        }

    float acc[16];
#pragma unroll
    for (int j = 0; j < 16; j++) acc[j] = 0.f;
#pragma unroll
    for (int s = 0; s < 8; s++) {
        const f16* op = Opart16 + ((((size_t)s * 256 + slot) * 4 + w) * 64 + lane) * 16;
        union { uint4 u; f16 h[8]; } p0, p1;
        p0.u = *(const uint4*)op;
        p1.u = *(const uint4*)(op + 8);
#pragma unroll
        for (int dt = 0; dt < 2; dt++)
#pragma unroll
            for (int i = 0; i < 4; i++) acc[dt * 4 + i] += wgt[s][i] * (float)p0.h[dt * 4 + i];
#pragma unroll
        for (int dt = 2; dt < 4; dt++)
#pragma unroll
            for (int i = 0; i < 4; i++) acc[dt * 4 + i] += wgt[s][i] * (float)p1.h[(dt - 2) * 4 + i];
    }
    float inv[4];
#pragma unroll
    for (int i = 0; i < 4; i++) inv[i] = 1.0f / L[i];
#pragma unroll
    for (int dt = 0; dt < 4; dt++)
#pragma unroll
        for (int i = 0; i < 4; i++)
            ctxbf[(size_t)(nbase + i) * 256 + h * 64 + dt * 16 + ln] = (f16)(acc[dt * 4 + i] * inv[i]);
}

// ---------------- layernorm (+optional fused top-1 router) ----------------
template <int DO_ROUTER>
__global__ __launch_bounds__(256) void ln_k(const float* __restrict__ X,
                                            const float* __restrict__ R,
                                            const float* __restrict__ gam,
                                            const float* __restrict__ bet,
                                            float* __restrict__ Of, f16* __restrict__ Oh, int doGelu,
                                            const float* __restrict__ grad,
                                            const float* __restrict__ Wr,
                                            const float* __restrict__ br,
                                            int* __restrict__ eid, float* __restrict__ gval) {
    __shared__ float sm[4];
    __shared__ float smr[16];
    int n = blockIdx.x, c = threadIdx.x;
    float x = X[(size_t)n * DMODEL + c];
    if (R) x += R[(size_t)n * DMODEL + c];
    float s = x;
    for (int off = 32; off; off >>= 1) s += __shfl_down(s, off);
    if ((c & 63) == 0) sm[c >> 6] = s;
    __syncthreads();
    float mean = (sm[0] + sm[1] + sm[2] + sm[3]) * (1.0f / DMODEL);
    float d = x - mean;
    float s2 = d * d;
    for (int off = 32; off; off >>= 1) s2 += __shfl_down(s2, off);
    __syncthreads();
    if ((c & 63) == 0) sm[c >> 6] = s2;
    __syncthreads();
    float var = (sm[0] + sm[1] + sm[2] + sm[3]) * (1.0f / DMODEL);
    float y = d * rsqrtf(var + 1e-5f) * gam[c] + bet[c];
    if (doGelu) y = gelu_exact(y);
    size_t idx = (size_t)n * DMODEL + c;
    if (Of) Of[idx] = y;
    if (Oh) Oh[idx] = (f16)y;

    if (DO_ROUTER) {
        float p0 = y * Wr[c * 4 + 0], p1 = y * Wr[c * 4 + 1];
        float p2 = y * Wr[c * 4 + 2], p3 = y * Wr[c * 4 + 3];
        for (int off = 32; off; off >>= 1) {
            p0 += __shfl_down(p0, off);
            p1 += __shfl_down(p1, off);
            p2 += __shfl_down(p2, off);
            p3 += __shfl_down(p3, off);
        }
        int wv = c >> 6;
        if ((c & 63) == 0) {
            smr[wv * 4 + 0] = p0; smr[wv * 4 + 1] = p1;
            smr[wv * 4 + 2] = p2; smr[wv * 4 + 3] = p3;
        }
        __syncthreads();
        if (c == 0) {
            float gv = grad[n];
            float l[4];
#pragma unroll
            for (int e = 0; e < 4; e++)
                l[e] = smr[e] + smr[4 + e] + smr[8 + e] + smr[12 + e] + gv * Wr[256 * 4 + e] + br[e];
            float mx = fmaxf(fmaxf(l[0], l[1]), fmaxf(l[2], l[3]));
            float ex[4], ssum = 0;
#pragma unroll
            for (int e = 0; e < 4; e++) { ex[e] = __expf(l[e] - mx); ssum += ex[e]; }
            int am = 0;
            float best = l[0];
#pragma unroll
            for (int e = 1; e < 4; e++)
                if (l[e] > best) { best = l[e]; am = e; }
            eid[n] = am;
            gval[n] = ex[am] / ssum;
        }
    }
}

// ---------------- MoE compaction: 128-aligned per-expert segments ----------------
__global__ __launch_bounds__(256) void compact_k(const int* __restrict__ eid,
                                                 int* __restrict__ gidx,
                                                 int* __restrict__ temap) {
    __shared__ int cnt[4], poff[4], cur[4];
    int t = threadIdx.x;
    if (t < 4) cnt[t] = 0;
    __syncthreads();
    for (int it = 0; it < 16; it++)
        atomicAdd(&cnt[eid[it * 256 + t]], 1);
    __syncthreads();
    if (t == 0) {
        int o = 0;
        for (int e = 0; e < 4; e++) {
            poff[e] = o;
            cur[e] = o;
            o += (cnt[e] + 127) & ~127;
        }
    }
    __syncthreads();
    if (t < 36) {
        int e = 0;
        for (int x = 0; x < 4; x++) {
            int seg0 = poff[x] >> 7;
            int seg1 = (poff[x] + ((cnt[x] + 127) & ~127)) >> 7;
            if (t >= seg0 && t < seg1) e = x;
        }
        temap[t] = e;
    }
    for (int i = t; i < 4608; i += 256) gidx[i] = -1;
    __syncthreads();
    for (int it = 0; it < 16; it++) {
        int n = it * 256 + t;
        int slot = atomicAdd(&cur[eid[n]], 1);
        gidx[slot] = n;
    }
}

// ---------------- functional head final ----------------
__global__ __launch_bounds__(256) void ghead_k(const f16* __restrict__ f,
                                               const float* __restrict__ Wf2,
                                               const float* __restrict__ bf2,
                                               float* __restrict__ out) {
    int n = blockIdx.x * 256 + threadIdx.x;
    float s = bf2[0];
#pragma unroll
    for (int c = 0; c < 8; c++) {
        union { uint4 u; f16 h[8]; } t;
        t.u = *(const uint4*)(f + (size_t)n * 64 + c * 8);
#pragma unroll
        for (int j = 0; j < 8; j++) s = fmaf((float)t.h[j], Wf2[c * 8 + j], s);
    }
    out[n] = 1.0f / (1.0f + expf(-s));
}

// ---------------- launch ----------------
extern "C" void kernel_launch(void* const* d_in, const int* in_sizes, int n_in,
                              void* d_out, int out_size, void* d_ws, size_t ws_size,
                              hipStream_t stream) {
    const float* vis   = (const float*)d_in[0];
    const float* pos   = (const float*)d_in[1];
    const float* grad  = (const float*)d_in[2];
    const float* Bf    = (const float*)d_in[3];
    const float* W_img = (const float*)d_in[4];
    const float* b_img = (const float*)d_in[5];
    const float* W_pos = (const float*)d_in[6];
    const float* b_pos = (const float*)d_in[7];
    const float* Wq = (const float*)d_in[8];  const float* bq = (const float*)d_in[9];
    const float* Wk = (const float*)d_in[10]; const float* bk = (const float*)d_in[11];
    const float* Wv = (const float*)d_in[12]; const float* bv = (const float*)d_in[13];
    const float* Wo = (const float*)d_in[14]; const float* bo = (const float*)d_in[15];
    const float* ln1g = (const float*)d_in[16]; const float* ln1b = (const float*)d_in[17];
    const float* Wr = (const float*)d_in[18]; const float* br = (const float*)d_in[19];
    const float* W1e = (const float*)d_in[20]; const float* b1e = (const float*)d_in[21];
    const float* W2e = (const float*)d_in[22]; const float* b2e = (const float*)d_in[23];
    const float* Wg1 = (const float*)d_in[24]; const float* bg1 = (const float*)d_in[25];
    const float* lngg = (const float*)d_in[26]; const float* lngb = (const float*)d_in[27];
    const float* Wg2 = (const float*)d_in[28]; const float* bg2 = (const float*)d_in[29];
    const float* Wf1 = (const float*)d_in[30]; const float* bf1 = (const float*)d_in[31];
    const float* Wf2 = (const float*)d_in[32]; const float* bf2 = (const float*)d_in[33];

    float* out = (float*)d_out;
    float* outMu = out;
    float* outTh = out + (size_t)NTOK * G_GENES;
    float* outG  = out + (size_t)2 * NTOK * G_GENES;

    // ---- workspace ----
    char* base = (char*)d_ws;
    size_t off = 0;
    auto A8 = [&](size_t bytes) { char* p = base + off; off += (bytes + 255) & ~(size_t)255; return p; };

    // region1 (16 MB): Abig (encoder A, 9.4MB) -> Opart16 (flash f16 partials, 16MB)
    char* reg1 = A8(16 * 1024 * 1024);
    f16* Abig    = (f16*)reg1;
    f16* Opart16 = (f16*)reg1;
    // region2 (20 MB): qkvbf @0 (6.3MB, alive through flash); hh @8MB (9.4MB, MoE)
    char* reg2 = A8(20 * 1024 * 1024);
    f16* qkvbf = (f16*)reg2;
    f16* hh    = (f16*)(reg2 + 8 * 1024 * 1024);

    f16* WtEnc = (f16*)A8((size_t)256 * 1152 * 2);
    f16* Wqkvt = (f16*)A8((size_t)768 * 256 * 2);
    f16* Wot   = (f16*)A8((size_t)256 * 256 * 2);
    f16* W1t   = (f16*)A8((size_t)4 * 1024 * 256 * 2);
    f16* W2t   = (f16*)A8((size_t)4 * 256 * 1024 * 2);
    f16* Wgft  = (f16*)A8((size_t)320 * 256 * 2);   // Wg1^T (256 rows) ++ Wf1^T (64 rows)
    f16* Wg2t  = (f16*)A8((size_t)4000 * 256 * 2);
    f16* Vt    = (f16*)A8((size_t)256 * NTOK * 2);
    float2* mlpart = (float2*)A8((size_t)32 * NTOK * 8);
    float* benc    = (float*)A8(256 * 4);
    float* biasqkv = (float*)A8(768 * 4);
    float* bgf     = (float*)A8(320 * 4);
    float* z    = (float*)A8((size_t)NTOK * DMODEL * 4);
    float* z2   = (float*)A8((size_t)NTOK * DMODEL * 4);
    float* attn = (float*)A8((size_t)NTOK * DMODEL * 4);
    float* tbuf = (float*)A8((size_t)NTOK * DMODEL * 4);
    f16* zbf    = (f16*)A8((size_t)NTOK * DMODEL * 2);
    f16* z2bf   = (f16*)A8((size_t)NTOK * DMODEL * 2);
    f16* z3bf   = (f16*)A8((size_t)NTOK * DMODEL * 2);
    f16* ctxbf  = (f16*)A8((size_t)NTOK * DMODEL * 2);
    f16* dbufbf = (f16*)A8((size_t)NTOK * DMODEL * 2);
    f16* fbf    = (f16*)A8((size_t)NTOK * 64 * 2);
    int* eidb   = (int*)A8(NTOK * 4);
    float* gval = (float*)A8(NTOK * 4);
    int* gidx   = (int*)A8(4608 * 4);
    int* temap  = (int*)A8(64 * 4);

    dim3 blk(256);

    // ---- weight prep ----
    TDs td;
    int nd = 0, pre = 0;
    auto addT = [&](const float* s, f16* d, int R, int C, int ldo) {
        td.t[nd] = TD{s, d, R, C, ldo};
        td.pre[nd] = pre;
        pre += (R >> 5) * (C >> 5);
        nd++;
    };
    addT(W_img, WtEnc, 1024, 256, 1152);
    addT(W_pos, WtEnc + 1024, 128, 256, 1152);
    addT(Wq, Wqkvt, 256, 256, 256);
    addT(Wk, Wqkvt + 256 * 256, 256, 256, 256);
    addT(Wv, Wqkvt + 512 * 256, 256, 256, 256);
    addT(Wo, Wot, 256, 256, 256);
    for (int e = 0; e < 4; e++) addT(W1e + (size_t)e * 262144, W1t + (size_t)e * 262144, 256, 1024, 256);
    for (int e = 0; e < 4; e++) addT(W2e + (size_t)e * 262144, W2t + (size_t)e * 262144, 1024, 256, 1024);
    addT(Wg1, Wgft, 256, 256, 256);
    addT(Wf1, Wgft + 256 * 256, 256, 64, 256);
    addT(Wg2, Wg2t, 256, 4000, 256);
    td.pre[nd] = pre;
    tconv_k<<<pre, blk, 0, stream>>>(td);
    setup_k<<<1, blk, 0, stream>>>(b_img, b_pos, bq, bk, bv, bg1, bf1, benc, biasqkv, bgf);

    // ---- encoder ----
    encin_k<<<NTOK, blk, 0, stream>>>(vis, pos, Bf, Abig);
    bgemm_k<1, EPI_DUAL, 0><<<dim3(32, 8, 1), blk, 0, stream>>>(
        Abig, 1152, WtEnc, 1152, benc, z, zbf, 256, 256, 1152,
        0, 0, nullptr, nullptr, nullptr, nullptr, nullptr, nullptr);

    // ---- fused QKV ----
    bgemm_k<2, EPI_F16, 0><<<dim3(32, 12, 1), blk, 0, stream>>>(
        zbf, 256, Wqkvt, 256, biasqkv, nullptr, qkvbf, 768, 768, 256,
        0, 0, nullptr, nullptr, nullptr, nullptr, nullptr, nullptr);
    tconvh_k<<<dim3(128, 8, 1), blk, 0, stream>>>(qkvbf + 512, 768, Vt, 4096);

    // ---- flash attention (split-KV x8) + combine ----
    flash_k<<<dim3(64, 4, 8), blk, 0, stream>>>(qkvbf, Vt, Opart16, mlpart);
    fcomb_k<<<256, blk, 0, stream>>>(Opart16, mlpart, ctxbf);
    bgemm_k<1, EPI_F32, 0><<<dim3(32, 8, 1), blk, 0, stream>>>(
        ctxbf, 256, Wot, 256, bo, attn, nullptr, 256, 256, 256,
        0, 0, nullptr, nullptr, nullptr, nullptr, nullptr, nullptr);
    // ln1 + fused router
    ln_k<1><<<NTOK, blk, 0, stream>>>(z, attn, ln1g, ln1b, z2, z2bf, 0, grad, Wr, br, eidb, gval);

    // ---- MoE: top-1 gather -> grouped GEMMs -> scatter ----
    compact_k<<<1, blk, 0, stream>>>(eidb, gidx, temap);
    bgemm_k<4, EPI_GELU_F16, 1><<<dim3(36, 8, 1), blk, 0, stream>>>(
        z2bf, 256, W1t, 256, b1e, nullptr, hh, 1024, 1024, 256,
        262144, 1024, gidx, temap, nullptr, nullptr, nullptr, nullptr);
    bgemm_k<2, EPI_MOESC, 2><<<dim3(36, 4, 1), blk, 0, stream>>>(
        hh, 1024, W2t, 1024, b2e, nullptr, z3bf, 256, 256, 1024,
        262144, 256, gidx, temap, z2, gval, nullptr, nullptr);

    // ---- gene decoder + functional head first layer (fused N=320 GEMM) ----
    bgemm_k<1, EPI_GF, 0><<<dim3(32, 10, 1), blk, 0, stream>>>(
        z3bf, 256, Wgft, 256, bgf, tbuf, fbf, 256, 320, 256,
        0, 0, nullptr, nullptr, nullptr, nullptr, nullptr, nullptr);
    ln_k<0><<<NTOK, blk, 0, stream>>>(tbuf, nullptr, lngg, lngb, nullptr, dbufbf, 1,
                                      nullptr, nullptr, nullptr, nullptr, nullptr);
    bgemm_k<4, EPI_GENE, 0><<<dim3(32, 32, 1), blk, 0, stream>>>(
        dbufbf, 256, Wg2t, 256, bg2, nullptr, nullptr, 4000, 4000, 256,
        0, 0, nullptr, nullptr, nullptr, nullptr, outMu, outTh);

    // ---- functional head final ----
    ghead_k<<<NTOK / 256, blk, 0, stream>>>(fbf, Wf2, bf2, outG);
}

// Round 6
// 437.085 us; speedup vs baseline: 1.0963x; 1.0963x over previous
//
#include <hip/hip_runtime.h>
#include <math.h>

#define NTOK 4096
#define DMODEL 256
#define G_GENES 2000

typedef _Float16 f16;
typedef _Float16 f16x2 __attribute__((ext_vector_type(2)));
typedef _Float16 f16x8 __attribute__((ext_vector_type(8)));
typedef float f32x4 __attribute__((ext_vector_type(4)));

// ---------------- helpers ----------------
__device__ __forceinline__ float gelu_exact(float x) {
    return 0.5f * x * (1.0f + erff(x * 0.70710678118654752f));
}
__device__ __forceinline__ float softplus_fast(float x) {
    return fmaxf(x, 0.0f) + __logf(1.0f + __expf(-fabsf(x)));
}
__device__ __forceinline__ unsigned pkf16(float a, float b) {
    union { f16x2 h; unsigned u; } t;
    t.h = (f16x2){(f16)a, (f16)b};
    return t.u;
}

// ---------------- encoder input build: vis cvt + fourier ----------------
__global__ __launch_bounds__(256) void encin_k(const float* __restrict__ vis,
                                               const float* __restrict__ pos,
                                               const float* __restrict__ B,
                                               f16* __restrict__ Abig) {
    int n = blockIdx.x, t = threadIdx.x;
    float4 v = *(const float4*)(vis + (size_t)n * 1024 + t * 4);
    union { ushort4 u; f16 h[4]; } o;
    o.h[0] = (f16)v.x; o.h[1] = (f16)v.y; o.h[2] = (f16)v.z; o.h[3] = (f16)v.w;
    *(ushort4*)(Abig + (size_t)n * 1152 + t * 4) = o.u;
    if (t < 64) {
        float xp = 6.283185307179586f *
                   (pos[n * 3 + 0] * B[t] + pos[n * 3 + 1] * B[64 + t] + pos[n * 3 + 2] * B[128 + t]);
        Abig[(size_t)n * 1152 + 1024 + t] = (f16)sinf(xp);
        Abig[(size_t)n * 1152 + 1088 + t] = (f16)cosf(xp);
    }
}

// ---------------- batched transpose-convert, flat tile list ----------------
struct TD { const float* s; f16* d; int R, C; int ldo; };
struct TDs { TD t[17]; int pre[18]; };
__global__ __launch_bounds__(256) void tconv_k(TDs ds) {
    int bid = blockIdx.x;
    int ti = 0;
#pragma unroll
    for (int i = 0; i < 17; i++)
        if (bid >= ds.pre[i + 1]) ti = i + 1;
    TD td = ds.t[ti];
    int local = bid - ds.pre[ti];
    int yt = td.C >> 5;
    int r0 = (local / yt) << 5;
    int c0 = (local % yt) << 5;
    __shared__ float tile[32][33];
    int tx = threadIdx.x & 31, ty = threadIdx.x >> 5;
#pragma unroll
    for (int i = 0; i < 32; i += 8)
        tile[ty + i][tx] = td.s[(size_t)(r0 + ty + i) * td.C + c0 + tx];
    __syncthreads();
#pragma unroll
    for (int i = 0; i < 32; i += 8)
        td.d[(size_t)(c0 + ty + i) * td.ldo + r0 + tx] = (f16)tile[tx][ty + i];
}

// ---------------- f16 transpose (V^T from qkv buffer) ----------------
__global__ __launch_bounds__(256) void tconvh_k(const f16* __restrict__ src, int ldin,
                                                f16* __restrict__ dst, int ldo) {
    __shared__ f16 tile[32][33];
    int r0 = blockIdx.x * 32, c0 = blockIdx.y * 32;
    int tx = threadIdx.x & 31, ty = threadIdx.x >> 5;
#pragma unroll
    for (int i = 0; i < 32; i += 8)
        tile[ty + i][tx] = src[(size_t)(r0 + ty + i) * ldin + c0 + tx];
    __syncthreads();
#pragma unroll
    for (int i = 0; i < 32; i += 8)
        dst[(size_t)(c0 + ty + i) * ldo + r0 + tx] = tile[tx][ty + i];
}

// ---------------- setup: fused bias vectors ----------------
__global__ __launch_bounds__(256) void setup_k(const float* b_img, const float* b_pos,
                                               const float* bq, const float* bk, const float* bv,
                                               const float* bg1, const float* bf1,
                                               float* benc, float* biasqkv, float* bgf) {
    int t = threadIdx.x;
    benc[t] = b_img[t] + b_pos[t];
    biasqkv[t] = bq[t];
    biasqkv[256 + t] = bk[t];
    biasqkv[512 + t] = bv[t];
    bgf[t] = bg1[t];
    if (t < 64) bgf[256 + t] = bf1[t];
}

// ---------------- MFMA f16 GEMM ----------------
#define EPI_F32 0
#define EPI_DUAL 1
#define EPI_F16 2
#define EPI_GELU_F16 3
#define EPI_GENE 4
#define EPI_MOESC 5
#define EPI_GF 6

template <int MTN, int EPI, int MODE>
__global__ __launch_bounds__(256) void bgemm_k(
    const f16* __restrict__ A, int lda,
    const f16* __restrict__ B, int ldb,
    const float* __restrict__ bias,
    float* __restrict__ Cf, f16* __restrict__ Ch, int ldc,
    int Ncols, int K,
    size_t eB, size_t eBias,
    const int* __restrict__ gidx, const int* __restrict__ temap,
    const float* __restrict__ z2, const float* __restrict__ gval,
    float* __restrict__ outMu, float* __restrict__ outTheta) {
    constexpr int BN = MTN * 32;
    __shared__ __align__(16) char smem[(128 + BN) * 72 * 2];
    f16 (*As)[72] = (f16(*)[72])smem;
    f16 (*Bs)[72] = (f16(*)[72])(smem + (size_t)128 * 72 * 2);

    const int tid = threadIdx.x;
    const int m0 = blockIdx.x * 128;
    const int n0 = blockIdx.y * BN;
    const int w = tid >> 6, lane = tid & 63;
    const int wr = w >> 1, wc = w & 1;
    const int ln = lane & 15, lg = lane >> 4;
    const int sr = tid >> 3;
    const int sc = (tid & 7) * 8;

    if (MODE == 1 || MODE == 2) {
        int e = temap[blockIdx.x];
        B += (size_t)e * eB;
        if (bias) bias += (size_t)e * eBias;
    }

    int grows[4];
#pragma unroll
    for (int i = 0; i < 4; i++) {
        int r = m0 + sr + i * 32;
        if (MODE == 1) {
            int g = gidx[r];
            grows[i] = (g < 0) ? 0 : g;
        } else {
            grows[i] = r;
        }
    }

    f32x4 acc[4][MTN];
    f32x4 zf = {0.f, 0.f, 0.f, 0.f};
#pragma unroll
    for (int i = 0; i < 4; i++)
#pragma unroll
        for (int j = 0; j < MTN; j++) acc[i][j] = zf;

    for (int k0 = 0; k0 < K; k0 += 64) {
#pragma unroll
        for (int i = 0; i < 4; i++) {
            uint4 v = *(const uint4*)(A + (size_t)grows[i] * lda + k0 + sc);
            int r = sr + i * 32;
            *(uint2*)&As[r][sc] = make_uint2(v.x, v.y);
            *(uint2*)&As[r][sc + 4] = make_uint2(v.z, v.w);
        }
#pragma unroll
        for (int i = 0; i < MTN; i++) {
            int r = sr + i * 32;
            uint4 v = make_uint4(0, 0, 0, 0);
            if (n0 + r < Ncols) v = *(const uint4*)(B + (size_t)(n0 + r) * ldb + k0 + sc);
            *(uint2*)&Bs[r][sc] = make_uint2(v.x, v.y);
            *(uint2*)&Bs[r][sc + 4] = make_uint2(v.z, v.w);
        }
        __syncthreads();
#pragma unroll
        for (int ks = 0; ks < 64; ks += 32) {
            f16x8 a[4], b[MTN];
#pragma unroll
            for (int t = 0; t < 4; t++) {
                const f16* p = &As[wr * 64 + t * 16 + ln][ks + lg * 8];
                union { f16x8 f; uint2 u[2]; } tmp;
                tmp.u[0] = *(const uint2*)p;
                tmp.u[1] = *(const uint2*)(p + 4);
                a[t] = tmp.f;
            }
#pragma unroll
            for (int t = 0; t < MTN; t++) {
                const f16* p = &Bs[wc * (MTN * 16) + t * 16 + ln][ks + lg * 8];
                union { f16x8 f; uint2 u[2]; } tmp;
                tmp.u[0] = *(const uint2*)p;
                tmp.u[1] = *(const uint2*)(p + 4);
                b[t] = tmp.f;
            }
#pragma unroll
            for (int tm = 0; tm < 4; tm++)
#pragma unroll
                for (int tn = 0; tn < MTN; tn++)
                    acc[tm][tn] = __builtin_amdgcn_mfma_f32_16x16x32_f16(a[tm], b[tn], acc[tm][tn], 0, 0, 0);
        }
        __syncthreads();
    }

    if (EPI == EPI_GENE) {
        float bval[MTN];
#pragma unroll
        for (int tn = 0; tn < MTN; tn++) {
            int col = n0 + wc * (MTN * 16) + tn * 16 + ln;
            bval[tn] = (col < Ncols) ? bias[col] : 0.0f;
        }
        float* Cs = (float*)smem;
        const int rrow = tid >> 3;
        const int rseg = tid & 7;
#pragma unroll
        for (int tm = 0; tm < 4; tm++) {
            __syncthreads();
#pragma unroll
            for (int tn = 0; tn < MTN; tn++) {
                int lc = wc * (MTN * 16) + tn * 16 + ln;
#pragma unroll
                for (int i = 0; i < 4; i++) {
                    int lr = wr * 16 + lg * 4 + i;
                    Cs[lr * 132 + lc] = acc[tm][tn][i] + bval[tn];
                }
            }
            __syncthreads();
            int grow = m0 + ((rrow >> 4) * 64) + tm * 16 + (rrow & 15);
            const float* cr = &Cs[rrow * 132 + rseg * 16];
            float mu[8], th[8];
#pragma unroll
            for (int g = 0; g < 8; g++) {
                mu[g] = softplus_fast(cr[2 * g]);
                th[g] = softplus_fast(cr[2 * g + 1]) + 1e-6f;
            }
            int gbase = (n0 + rseg * 16) >> 1;
            float* mp = outMu + (size_t)grow * G_GENES + gbase;
            float* tp = outTheta + (size_t)grow * G_GENES + gbase;
            if (gbase + 8 <= G_GENES) {
                *(float4*)mp = make_float4(mu[0], mu[1], mu[2], mu[3]);
                *(float4*)(mp + 4) = make_float4(mu[4], mu[5], mu[6], mu[7]);
                *(float4*)tp = make_float4(th[0], th[1], th[2], th[3]);
                *(float4*)(tp + 4) = make_float4(th[4], th[5], th[6], th[7]);
            } else {
#pragma unroll
                for (int g = 0; g < 8; g++)
                    if (gbase + g < G_GENES) { mp[g] = mu[g]; tp[g] = th[g]; }
            }
        }
        return;
    }

#pragma unroll
    for (int tm = 0; tm < 4; tm++) {
#pragma unroll
        for (int tn = 0; tn < MTN; tn++) {
            int col = n0 + wc * (MTN * 16) + tn * 16 + ln;
            if (col >= Ncols) continue;
#pragma unroll
            for (int i = 0; i < 4; i++) {
                int row = m0 + wr * 64 + tm * 16 + lg * 4 + i;
                float v = acc[tm][tn][i];
                if (EPI == EPI_MOESC) {
                    int tok = gidx[row];
                    if (tok < 0) continue;
                    v += bias[col];
                    size_t oi = (size_t)tok * ldc + col;
                    Ch[oi] = (f16)(z2[oi] + gval[tok] * v);
                    continue;
                }
                if (EPI == EPI_GF) {
                    v += bias[col];
                    if (col < 256) Cf[(size_t)row * 256 + col] = v;
                    else Ch[(size_t)row * 64 + (col - 256)] = (f16)gelu_exact(v);
                    continue;
                }
                size_t idx = (size_t)row * ldc + col;
                if (EPI == EPI_F32) {
                    if (bias) v += bias[col];
                    Cf[idx] = v;
                } else if (EPI == EPI_DUAL) {
                    v += bias[col];
                    Cf[idx] = v;
                    Ch[idx] = (f16)v;
                } else if (EPI == EPI_F16) {
                    v += bias[col];
                    Ch[idx] = (f16)v;
                } else if (EPI == EPI_GELU_F16) {
                    v += bias[col];
                    Ch[idx] = (f16)gelu_exact(v);
                }
            }
        }
    }
}

// ---------------- flash attention v3: transposed S, shfl P-exchange, dbuf ----------------
// grid (64 q-tiles, 4 heads, 4 kv-splits); 256 thr = 4 waves; wave owns 16 Q rows.
// S^T = K·Q^T: C-layout col=ln=q-row, row=quad*4+i=kv  -> per-lane single-row softmax.
// O^T = V^T·P^T: A=V^T frag from LDS, B=P^T frag built via 6 shfl_xor.
// Opart16: [((s*256 + slot)*4 + w)*64 + lane]*16, lane-contiguous f16.
__global__ __launch_bounds__(256) void flash_k(const f16* __restrict__ qkv,
                                               const f16* __restrict__ Vt,
                                               f16* __restrict__ Opart16,
                                               float2* __restrict__ mlpart) {
    __shared__ f16 Kb[2][64][72];
    __shared__ f16 Vb[2][64][72];
    const int tid = threadIdx.x;
    const int w = tid >> 6, lane = tid & 63;
    const int ln = lane & 15, quad = lane >> 4;
    const int q0 = blockIdx.x * 64;
    const int hq = blockIdx.y * 64;
    const int kt0 = blockIdx.z * 16;

    // Q fragment (B-operand): lane = q-row, regs = d
    f16x8 qfrag[2];
    {
        const f16* qp = qkv + (size_t)(q0 + w * 16 + ln) * 768 + hq + quad * 8;
        union { f16x8 f; uint4 u; } t0, t1;
        t0.u = *(const uint4*)qp;
        t1.u = *(const uint4*)(qp + 32);
        qfrag[0] = t0.f; qfrag[1] = t1.f;
    }

    const int srow = tid >> 2;        // 0..63
    const int scol = (tid & 3) * 16;  // 0,16,32,48

    float m_run = -1e30f, l_run = 0.0f;
    f32x4 accO[4];
#pragma unroll
    for (int i = 0; i < 4; i++) accO[i] = (f32x4){0.f, 0.f, 0.f, 0.f};

    uint4 kA[2], vA[2], kB[2], vB[2];
    auto loadKV = [&](int kt, uint4* kr, uint4* vr) {
        const f16* kp = qkv + (size_t)(kt * 64 + srow) * 768 + 256 + hq + scol;
        const f16* vp = Vt + (size_t)(hq + srow) * 4096 + kt * 64 + scol;
        kr[0] = *(const uint4*)kp; kr[1] = *(const uint4*)(kp + 8);
        vr[0] = *(const uint4*)vp; vr[1] = *(const uint4*)(vp + 8);
    };
    auto stage = [&](int b, const uint4* kr, const uint4* vr) {
        *(uint4*)&Kb[b][srow][scol] = kr[0];
        *(uint4*)&Kb[b][srow][scol + 8] = kr[1];
        *(uint4*)&Vb[b][srow][scol] = vr[0];
        *(uint4*)&Vb[b][srow][scol + 8] = vr[1];
    };

    auto computeTile = [&](int b) {
        f32x4 accS[4];
#pragma unroll
        for (int nt = 0; nt < 4; nt++) {
            union { f16x8 f; uint4 u; } a0, a1;
            a0.u = *(const uint4*)&Kb[b][nt * 16 + ln][quad * 8];
            a1.u = *(const uint4*)&Kb[b][nt * 16 + ln][32 + quad * 8];
            f32x4 a = {0.f, 0.f, 0.f, 0.f};
            a = __builtin_amdgcn_mfma_f32_16x16x32_f16(a0.f, qfrag[0], a, 0, 0, 0);
            a = __builtin_amdgcn_mfma_f32_16x16x32_f16(a1.f, qfrag[1], a, 0, 0, 0);
            accS[nt] = a;
        }
        float mx = -1e30f;
#pragma unroll
        for (int nt = 0; nt < 4; nt++)
#pragma unroll
            for (int i = 0; i < 4; i++) {
                accS[nt][i] *= 0.125f;
                mx = fmaxf(mx, accS[nt][i]);
            }
        mx = fmaxf(mx, __shfl_xor(mx, 16));
        mx = fmaxf(mx, __shfl_xor(mx, 32));
        float mnew = fmaxf(m_run, mx);
        float rs = 0.0f;
#pragma unroll
        for (int nt = 0; nt < 4; nt++)
#pragma unroll
            for (int i = 0; i < 4; i++) {
                float p = __expf(accS[nt][i] - mnew);
                accS[nt][i] = p;
                rs += p;
            }
        rs += __shfl_xor(rs, 16);
        rs += __shfl_xor(rs, 32);
        float alpha = __expf(m_run - mnew);
        l_run = l_run * alpha + rs;
        m_run = mnew;
#pragma unroll
        for (int dt = 0; dt < 4; dt++)
#pragma unroll
            for (int i = 0; i < 4; i++) accO[dt][i] *= alpha;

        // P^T B-frag via cross-quad exchange (kv chunks of 32)
#pragma unroll
        for (int c = 0; c < 2; c++) {
            unsigned p0x = pkf16(accS[2 * c][0], accS[2 * c][1]);
            unsigned p0y = pkf16(accS[2 * c][2], accS[2 * c][3]);
            unsigned p1x = pkf16(accS[2 * c + 1][0], accS[2 * c + 1][1]);
            unsigned p1y = pkf16(accS[2 * c + 1][2], accS[2 * c + 1][3]);
            unsigned x16_0x = __shfl_xor((int)p0x, 16), x16_0y = __shfl_xor((int)p0y, 16);
            unsigned x32_0x = __shfl_xor((int)p0x, 32), x32_0y = __shfl_xor((int)p0y, 32);
            unsigned x48_0x = __shfl_xor((int)p0x, 48), x48_0y = __shfl_xor((int)p0y, 48);
            unsigned x16_1x = __shfl_xor((int)p1x, 16), x16_1y = __shfl_xor((int)p1y, 16);
            unsigned x32_1x = __shfl_xor((int)p1x, 32), x32_1y = __shfl_xor((int)p1y, 32);
            unsigned x48_1x = __shfl_xor((int)p1x, 48), x48_1y = __shfl_xor((int)p1y, 48);
            union { f16x8 f; unsigned u[4]; } pf;
            pf.u[0] = quad == 0 ? p0x : quad == 1 ? x48_0x : quad == 2 ? x32_1x : x16_1x;
            pf.u[1] = quad == 0 ? p0y : quad == 1 ? x48_0y : quad == 2 ? x32_1y : x16_1y;
            pf.u[2] = quad == 0 ? x16_0x : quad == 1 ? x32_0x : quad == 2 ? x48_1x : p1x;
            pf.u[3] = quad == 0 ? x16_0y : quad == 1 ? x32_0y : quad == 2 ? x48_1y : p1y;
#pragma unroll
            for (int dt = 0; dt < 4; dt++) {
                union { f16x8 f; uint4 u; } vf;
                vf.u = *(const uint4*)&Vb[b][dt * 16 + ln][c * 32 + quad * 8];
                accO[dt] = __builtin_amdgcn_mfma_f32_16x16x32_f16(vf.f, pf.f, accO[dt], 0, 0, 0);
            }
        }
    };

    loadKV(kt0, kA, vA);
    stage(0, kA, vA);
    loadKV(kt0 + 1, kB, vB);
    __syncthreads();
    for (int t = 0; t < 16; t += 2) {
        computeTile(0);                     // tile t
        stage(1, kB, vB);                   // tile t+1 -> buf1
        if (t + 2 < 16) loadKV(kt0 + t + 2, kA, vA);
        __syncthreads();
        computeTile(1);                     // tile t+1
        if (t + 2 < 16) stage(0, kA, vA);   // tile t+2 -> buf0
        if (t + 3 < 16) loadKV(kt0 + t + 3, kB, vB);
        __syncthreads();
    }

    // lane-contiguous f16 partial store: lane holds O^T[d=dt*16+quad*4+i][q=ln-row]
    const int slot = blockIdx.x * 4 + blockIdx.y;
    f16* op = Opart16 + ((((size_t)blockIdx.z * 256 + slot) * 4 + w) * 64 + lane) * 16;
    union { uint4 u; f16 h[8]; } pk0, pk1;
#pragma unroll
    for (int dt = 0; dt < 2; dt++)
#pragma unroll
        for (int i = 0; i < 4; i++) pk0.h[dt * 4 + i] = (f16)accO[dt][i];
#pragma unroll
    for (int dt = 2; dt < 4; dt++)
#pragma unroll
        for (int i = 0; i < 4; i++) pk1.h[(dt - 2) * 4 + i] = (f16)accO[dt][i];
    *(uint4*)op = pk0.u;
    *(uint4*)(op + 8) = pk1.u;
    if (quad == 0)
        mlpart[(size_t)(blockIdx.z * 4 + blockIdx.y) * NTOK + q0 + w * 16 + ln] =
            make_float2(m_run, l_run);
}

// ---------------- flash combine (de-swizzle, 4 splits): 256 blocks ----------------
__global__ __launch_bounds__(256) void fcomb_k(const f16* __restrict__ Opart16,
                                               const float2* __restrict__ mlpart,
                                               f16* __restrict__ ctxbf) {
    __shared__ f16 Os[4][16][72];
    const int slot = blockIdx.x;
    const int w = threadIdx.x >> 6, lane = threadIdx.x & 63;
    const int bx = slot >> 2, h = slot & 3;
    const int quad = lane >> 4, ln = lane & 15;
    const int q = bx * 64 + w * 16 + ln;

    float2 ml[4];
    float mmax = -1e30f;
#pragma unroll
    for (int s = 0; s < 4; s++) {
        ml[s] = mlpart[(size_t)(s * 4 + h) * NTOK + q];
        mmax = fmaxf(mmax, ml[s].x);
    }
    float L = 0.0f, wgt[4];
#pragma unroll
    for (int s = 0; s < 4; s++) {
        wgt[s] = __expf(ml[s].x - mmax);
        L += wgt[s] * ml[s].y;
    }
    float acc[16];
#pragma unroll
    for (int j = 0; j < 16; j++) acc[j] = 0.f;
#pragma unroll
    for (int s = 0; s < 4; s++) {
        const f16* op = Opart16 + ((((size_t)s * 256 + slot) * 4 + w) * 64 + lane) * 16;
        union { uint4 u; f16 hh[8]; } p0, p1;
        p0.u = *(const uint4*)op;
        p1.u = *(const uint4*)(op + 8);
#pragma unroll
        for (int j = 0; j < 8; j++) {
            acc[j] += wgt[s] * (float)p0.hh[j];
            acc[8 + j] += wgt[s] * (float)p1.hh[j];
        }
    }
    float inv = 1.0f / L;
    // stage O^T back to row-major via per-wave LDS (same-wave DS ordering)
#pragma unroll
    for (int dt = 0; dt < 4; dt++)
#pragma unroll
        for (int i = 0; i < 4; i++)
            Os[w][ln][dt * 16 + quad * 4 + i] = (f16)(acc[dt * 4 + i] * inv);
    union { uint4 u; f16 hh[8]; } o0, o1;
    o0.u = *(const uint4*)&Os[w][ln][quad * 16];
    o1.u = *(const uint4*)&Os[w][ln][quad * 16 + 8];
    f16* cp = ctxbf + (size_t)q * 256 + h * 64 + quad * 16;
    *(uint4*)cp = o0.u;
    *(uint4*)(cp + 8) = o1.u;
}

// ---------------- layernorm (+optional fused top-1 router) ----------------
template <int DO_ROUTER>
__global__ __launch_bounds__(256) void ln_k(const float* __restrict__ X,
                                            const float* __restrict__ R,
                                            const float* __restrict__ gam,
                                            const float* __restrict__ bet,
                                            float* __restrict__ Of, f16* __restrict__ Oh, int doGelu,
                                            const float* __restrict__ grad,
                                            const float* __restrict__ Wr,
                                            const float* __restrict__ br,
                                            int* __restrict__ eid, float* __restrict__ gval) {
    __shared__ float sm[4];
    __shared__ float smr[16];
    int n = blockIdx.x, c = threadIdx.x;
    float x = X[(size_t)n * DMODEL + c];
    if (R) x += R[(size_t)n * DMODEL + c];
    float s = x;
    for (int off = 32; off; off >>= 1) s += __shfl_down(s, off);
    if ((c & 63) == 0) sm[c >> 6] = s;
    __syncthreads();
    float mean = (sm[0] + sm[1] + sm[2] + sm[3]) * (1.0f / DMODEL);
    float d = x - mean;
    float s2 = d * d;
    for (int off = 32; off; off >>= 1) s2 += __shfl_down(s2, off);
    __syncthreads();
    if ((c & 63) == 0) sm[c >> 6] = s2;
    __syncthreads();
    float var = (sm[0] + sm[1] + sm[2] + sm[3]) * (1.0f / DMODEL);
    float y = d * rsqrtf(var + 1e-5f) * gam[c] + bet[c];
    if (doGelu) y = gelu_exact(y);
    size_t idx = (size_t)n * DMODEL + c;
    if (Of) Of[idx] = y;
    if (Oh) Oh[idx] = (f16)y;

    if (DO_ROUTER) {
        float p0 = y * Wr[c * 4 + 0], p1 = y * Wr[c * 4 + 1];
        float p2 = y * Wr[c * 4 + 2], p3 = y * Wr[c * 4 + 3];
        for (int off = 32; off; off >>= 1) {
            p0 += __shfl_down(p0, off);
            p1 += __shfl_down(p1, off);
            p2 += __shfl_down(p2, off);
            p3 += __shfl_down(p3, off);
        }
        int wv = c >> 6;
        if ((c & 63) == 0) {
            smr[wv * 4 + 0] = p0; smr[wv * 4 + 1] = p1;
            smr[wv * 4 + 2] = p2; smr[wv * 4 + 3] = p3;
        }
        __syncthreads();
        if (c == 0) {
            float gv = grad[n];
            float l[4];
#pragma unroll
            for (int e = 0; e < 4; e++)
                l[e] = smr[e] + smr[4 + e] + smr[8 + e] + smr[12 + e] + gv * Wr[256 * 4 + e] + br[e];
            float mx = fmaxf(fmaxf(l[0], l[1]), fmaxf(l[2], l[3]));
            float ex[4], ssum = 0;
#pragma unroll
            for (int e = 0; e < 4; e++) { ex[e] = __expf(l[e] - mx); ssum += ex[e]; }
            int am = 0;
            float best = l[0];
#pragma unroll
            for (int e = 1; e < 4; e++)
                if (l[e] > best) { best = l[e]; am = e; }
            eid[n] = am;
            gval[n] = ex[am] / ssum;
        }
    }
}

// ---------------- MoE compaction ----------------
__global__ __launch_bounds__(256) void compact_k(const int* __restrict__ eid,
                                                 int* __restrict__ gidx,
                                                 int* __restrict__ temap) {
    __shared__ int cnt[4], poff[4], cur[4];
    int t = threadIdx.x;
    if (t < 4) cnt[t] = 0;
    __syncthreads();
    for (int it = 0; it < 16; it++)
        atomicAdd(&cnt[eid[it * 256 + t]], 1);
    __syncthreads();
    if (t == 0) {
        int o = 0;
        for (int e = 0; e < 4; e++) {
            poff[e] = o;
            cur[e] = o;
            o += (cnt[e] + 127) & ~127;
        }
    }
    __syncthreads();
    if (t < 36) {
        int e = 0;
        for (int x = 0; x < 4; x++) {
            int seg0 = poff[x] >> 7;
            int seg1 = (poff[x] + ((cnt[x] + 127) & ~127)) >> 7;
            if (t >= seg0 && t < seg1) e = x;
        }
        temap[t] = e;
    }
    for (int i = t; i < 4608; i += 256) gidx[i] = -1;
    __syncthreads();
    for (int it = 0; it < 16; it++) {
        int n = it * 256 + t;
        int slot = atomicAdd(&cur[eid[n]], 1);
        gidx[slot] = n;
    }
}

// ---------------- functional head final ----------------
__global__ __launch_bounds__(256) void ghead_k(const f16* __restrict__ f,
                                               const float* __restrict__ Wf2,
                                               const float* __restrict__ bf2,
                                               float* __restrict__ out) {
    int n = blockIdx.x * 256 + threadIdx.x;
    float s = bf2[0];
#pragma unroll
    for (int c = 0; c < 8; c++) {
        union { uint4 u; f16 h[8]; } t;
        t.u = *(const uint4*)(f + (size_t)n * 64 + c * 8);
#pragma unroll
        for (int j = 0; j < 8; j++) s = fmaf((float)t.h[j], Wf2[c * 8 + j], s);
    }
    out[n] = 1.0f / (1.0f + expf(-s));
}

// ---------------- launch ----------------
extern "C" void kernel_launch(void* const* d_in, const int* in_sizes, int n_in,
                              void* d_out, int out_size, void* d_ws, size_t ws_size,
                              hipStream_t stream) {
    const float* vis   = (const float*)d_in[0];
    const float* pos   = (const float*)d_in[1];
    const float* grad  = (const float*)d_in[2];
    const float* Bf    = (const float*)d_in[3];
    const float* W_img = (const float*)d_in[4];
    const float* b_img = (const float*)d_in[5];
    const float* W_pos = (const float*)d_in[6];
    const float* b_pos = (const float*)d_in[7];
    const float* Wq = (const float*)d_in[8];  const float* bq = (const float*)d_in[9];
    const float* Wk = (const float*)d_in[10]; const float* bk = (const float*)d_in[11];
    const float* Wv = (const float*)d_in[12]; const float* bv = (const float*)d_in[13];
    const float* Wo = (const float*)d_in[14]; const float* bo = (const float*)d_in[15];
    const float* ln1g = (const float*)d_in[16]; const float* ln1b = (const float*)d_in[17];
    const float* Wr = (const float*)d_in[18]; const float* br = (const float*)d_in[19];
    const float* W1e = (const float*)d_in[20]; const float* b1e = (const float*)d_in[21];
    const float* W2e = (const float*)d_in[22]; const float* b2e = (const float*)d_in[23];
    const float* Wg1 = (const float*)d_in[24]; const float* bg1 = (const float*)d_in[25];
    const float* lngg = (const float*)d_in[26]; const float* lngb = (const float*)d_in[27];
    const float* Wg2 = (const float*)d_in[28]; const float* bg2 = (const float*)d_in[29];
    const float* Wf1 = (const float*)d_in[30]; const float* bf1 = (const float*)d_in[31];
    const float* Wf2 = (const float*)d_in[32]; const float* bf2 = (const float*)d_in[33];

    float* out = (float*)d_out;
    float* outMu = out;
    float* outTh = out + (size_t)NTOK * G_GENES;
    float* outG  = out + (size_t)2 * NTOK * G_GENES;

    // ---- workspace ----
    char* base = (char*)d_ws;
    size_t off = 0;
    auto A8 = [&](size_t bytes) { char* p = base + off; off += (bytes + 255) & ~(size_t)255; return p; };

    // region1 (16 MB): Abig (encoder A, 9.4MB) -> Opart16 (flash f16 partials, 8.4MB)
    char* reg1 = A8(16 * 1024 * 1024);
    f16* Abig    = (f16*)reg1;
    f16* Opart16 = (f16*)reg1;
    // region2 (20 MB): qkvbf @0 (6.3MB, alive through flash); hh @8MB (9.4MB, MoE)
    char* reg2 = A8(20 * 1024 * 1024);
    f16* qkvbf = (f16*)reg2;
    f16* hh    = (f16*)(reg2 + 8 * 1024 * 1024);

    f16* WtEnc = (f16*)A8((size_t)256 * 1152 * 2);
    f16* Wqkvt = (f16*)A8((size_t)768 * 256 * 2);
    f16* Wot   = (f16*)A8((size_t)256 * 256 * 2);
    f16* W1t   = (f16*)A8((size_t)4 * 1024 * 256 * 2);
    f16* W2t   = (f16*)A8((size_t)4 * 256 * 1024 * 2);
    f16* Wgft  = (f16*)A8((size_t)320 * 256 * 2);
    f16* Wg2t  = (f16*)A8((size_t)4000 * 256 * 2);
    f16* Vt    = (f16*)A8((size_t)256 * NTOK * 2);
    float2* mlpart = (float2*)A8((size_t)16 * NTOK * 8);
    float* benc    = (float*)A8(256 * 4);
    float* biasqkv = (float*)A8(768 * 4);
    float* bgf     = (float*)A8(320 * 4);
    float* z    = (float*)A8((size_t)NTOK * DMODEL * 4);
    float* z2   = (float*)A8((size_t)NTOK * DMODEL * 4);
    float* attn = (float*)A8((size_t)NTOK * DMODEL * 4);
    float* tbuf = (float*)A8((size_t)NTOK * DMODEL * 4);
    f16* zbf    = (f16*)A8((size_t)NTOK * DMODEL * 2);
    f16* z2bf   = (f16*)A8((size_t)NTOK * DMODEL * 2);
    f16* z3bf   = (f16*)A8((size_t)NTOK * DMODEL * 2);
    f16* ctxbf  = (f16*)A8((size_t)NTOK * DMODEL * 2);
    f16* dbufbf = (f16*)A8((size_t)NTOK * DMODEL * 2);
    f16* fbf    = (f16*)A8((size_t)NTOK * 64 * 2);
    int* eidb   = (int*)A8(NTOK * 4);
    float* gval = (float*)A8(NTOK * 4);
    int* gidx   = (int*)A8(4608 * 4);
    int* temap  = (int*)A8(64 * 4);

    dim3 blk(256);

    // ---- weight prep ----
    TDs td;
    int nd = 0, pre = 0;
    auto addT = [&](const float* s, f16* d, int R, int C, int ldo) {
        td.t[nd] = TD{s, d, R, C, ldo};
        td.pre[nd] = pre;
        pre += (R >> 5) * (C >> 5);
        nd++;
    };
    addT(W_img, WtEnc, 1024, 256, 1152);
    addT(W_pos, WtEnc + 1024, 128, 256, 1152);
    addT(Wq, Wqkvt, 256, 256, 256);
    addT(Wk, Wqkvt + 256 * 256, 256, 256, 256);
    addT(Wv, Wqkvt + 512 * 256, 256, 256, 256);
    addT(Wo, Wot, 256, 256, 256);
    for (int e = 0; e < 4; e++) addT(W1e + (size_t)e * 262144, W1t + (size_t)e * 262144, 256, 1024, 256);
    for (int e = 0; e < 4; e++) addT(W2e + (size_t)e * 262144, W2t + (size_t)e * 262144, 1024, 256, 1024);
    addT(Wg1, Wgft, 256, 256, 256);
    addT(Wf1, Wgft + 256 * 256, 256, 64, 256);
    addT(Wg2, Wg2t, 256, 4000, 256);
    td.pre[nd] = pre;
    tconv_k<<<pre, blk, 0, stream>>>(td);
    setup_k<<<1, blk, 0, stream>>>(b_img, b_pos, bq, bk, bv, bg1, bf1, benc, biasqkv, bgf);

    // ---- encoder ----
    encin_k<<<NTOK, blk, 0, stream>>>(vis, pos, Bf, Abig);
    bgemm_k<1, EPI_DUAL, 0><<<dim3(32, 8, 1), blk, 0, stream>>>(
        Abig, 1152, WtEnc, 1152, benc, z, zbf, 256, 256, 1152,
        0, 0, nullptr, nullptr, nullptr, nullptr, nullptr, nullptr);

    // ---- fused QKV ----
    bgemm_k<2, EPI_F16, 0><<<dim3(32, 12, 1), blk, 0, stream>>>(
        zbf, 256, Wqkvt, 256, biasqkv, nullptr, qkvbf, 768, 768, 256,
        0, 0, nullptr, nullptr, nullptr, nullptr, nullptr, nullptr);
    tconvh_k<<<dim3(128, 8, 1), blk, 0, stream>>>(qkvbf + 512, 768, Vt, 4096);

    // ---- flash attention (split-KV x4) + combine ----
    flash_k<<<dim3(64, 4, 4), blk, 0, stream>>>(qkvbf, Vt, Opart16, mlpart);
    fcomb_k<<<256, blk, 0, stream>>>(Opart16, mlpart, ctxbf);
    bgemm_k<1, EPI_F32, 0><<<dim3(32, 8, 1), blk, 0, stream>>>(
        ctxbf, 256, Wot, 256, bo, attn, nullptr, 256, 256, 256,
        0, 0, nullptr, nullptr, nullptr, nullptr, nullptr, nullptr);
    ln_k<1><<<NTOK, blk, 0, stream>>>(z, attn, ln1g, ln1b, z2, z2bf, 0, grad, Wr, br, eidb, gval);

    // ---- MoE: top-1 gather -> grouped GEMMs -> scatter ----
    compact_k<<<1, blk, 0, stream>>>(eidb, gidx, temap);
    bgemm_k<4, EPI_GELU_F16, 1><<<dim3(36, 8, 1), blk, 0, stream>>>(
        z2bf, 256, W1t, 256, b1e, nullptr, hh, 1024, 1024, 256,
        262144, 1024, gidx, temap, nullptr, nullptr, nullptr, nullptr);
    bgemm_k<1, EPI_MOESC, 2><<<dim3(36, 8, 1), blk, 0, stream>>>(
        hh, 1024, W2t, 1024, b2e, nullptr, z3bf, 256, 256, 1024,
        262144, 256, gidx, temap, z2, gval, nullptr, nullptr);

    // ---- gene decoder + functional head first layer (fused N=320 GEMM) ----
    bgemm_k<1, EPI_GF, 0><<<dim3(32, 10, 1), blk, 0, stream>>>(
        z3bf, 256, Wgft, 256, bgf, tbuf, fbf, 256, 320, 256,
        0, 0, nullptr, nullptr, nullptr, nullptr, nullptr, nullptr);
    ln_k<0><<<NTOK, blk, 0, stream>>>(tbuf, nullptr, lngg, lngb, nullptr, dbufbf, 1,
                                      nullptr, nullptr, nullptr, nullptr, nullptr);
    bgemm_k<4, EPI_GENE, 0><<<dim3(32, 32, 1), blk, 0, stream>>>(
        dbufbf, 256, Wg2t, 256, bg2, nullptr, nullptr, 4000, 4000, 256,
        0, 0, nullptr, nullptr, nullptr, nullptr, outMu, outTh);

    // ---- functional head final ----
    ghead_k<<<NTOK / 256, blk, 0, stream>>>(fbf, Wf2, bf2, outG);
}